// Round 8
// baseline (220.496 us; speedup 1.0000x reference)
//
#include <hip/hip_runtime.h>
#include <cstdint>

// EncoderDecoderAttention: B=2, S=2048, E=1024, H=16, Dh=64
// fused convs -> counted-vmcnt dbuf QKV GEMM -> 64q/wave LDS-staged attention
// (counted-vmcnt dbuf, in-register softmax) -> counted-vmcnt dbuf out GEMM

typedef unsigned short u16;
typedef unsigned int   u32;
typedef __bf16 bf16x8 __attribute__((ext_vector_type(8)));
typedef float  f32x4  __attribute__((ext_vector_type(4)));
typedef float  f32x16 __attribute__((ext_vector_type(16)));

#define SEQ 2048
#define EMB 1024
#define NROWS 4096
// Q pre-scale: (1/sqrt(64)) * log2(e)
#define QSCL 0.18033688011112042f

__device__ __forceinline__ u16 f2b(float f) {
    u32 u = __builtin_bit_cast(u32, f);
    return (u16)((u + 0x7FFFu + ((u >> 16) & 1u)) >> 16);
}

__device__ __forceinline__ u32 cvtpk(float a, float b) {
    u32 r; asm("v_cvt_pk_bf16_f32 %0, %1, %2" : "=v"(r) : "v"(a), "v"(b)); return r;
}

__device__ __forceinline__ float exp2g(float x) {
    float r; asm("v_exp_f32 %0, %1" : "=v"(r) : "v"(x)); return r;
}

__device__ __forceinline__ int swz_off(int lin) {
    int row = lin >> 6;
    return lin ^ ((((row) + (row >> 2)) & 3) << 4);
}

#define GLDS16(src, dst) __builtin_amdgcn_global_load_lds( \
    (const __attribute__((address_space(1))) void*)(src),  \
    (__attribute__((address_space(3))) void*)(dst), 16, 0, 0)

#define VMCNT(n) asm volatile("s_waitcnt vmcnt(" #n ")" ::: "memory")
#define SBAR()   __builtin_amdgcn_s_barrier()
#define SCHED0() __builtin_amdgcn_sched_barrier(0)

// ---- fused elementwise f32 -> bf16 for both activations ----
__global__ __launch_bounds__(256) void convx2_kernel(const float* __restrict__ a,
                                                     const float* __restrict__ b,
                                                     u16* __restrict__ oa,
                                                     u16* __restrict__ ob) {
    int i = blockIdx.x * 256 + threadIdx.x;     // 0 .. 2M-1
    const float* src; u16* dst; int j;
    if (i < 1048576) { src = a; dst = oa; j = i; }
    else             { src = b; dst = ob; j = i - 1048576; }
    float4 v = ((const float4*)src)[j];
    uint2 o;
    o.x = (u32)f2b(v.x) | ((u32)f2b(v.y) << 16);
    o.y = (u32)f2b(v.z) | ((u32)f2b(v.w) << 16);
    ((uint2*)dst)[j] = o;
}

// ---- fused weight transpose to [N][K] bf16 via LDS 64x64 tiles ----
__global__ __launch_bounds__(256) void convw4_kernel(const float* __restrict__ wq,
                                                     const float* __restrict__ wk,
                                                     const float* __restrict__ wv,
                                                     const float* __restrict__ wo,
                                                     u16* __restrict__ oq,
                                                     u16* __restrict__ ok,
                                                     u16* __restrict__ ov,
                                                     u16* __restrict__ oo) {
    __shared__ u16 T[64][72];
    int which = blockIdx.x >> 8, tile = blockIdx.x & 255;
    const float* in = (which == 0) ? wq : (which == 1) ? wk : (which == 2) ? wv : wo;
    u16* out = (which == 0) ? oq : (which == 1) ? ok : (which == 2) ? ov : oo;
    int mode = (which == 3) ? 1 : 0;
    int r  = threadIdx.x >> 2;
    int c0 = (threadIdx.x & 3) * 16;
    int h = 0, e0, n0 = 0;
    size_t srcBase; int srcStride;
    if (mode == 0) { h = tile >> 4; e0 = (tile & 15) * 64; srcBase = ((size_t)h * 1024 + e0) * 64; srcStride = 64; }
    else           { n0 = (tile >> 4) * 64; e0 = (tile & 15) * 64; srcBase = (size_t)e0 * 1024 + n0; srcStride = 1024; }
    const float* src = in + srcBase + (size_t)r * srcStride + c0;
    #pragma unroll
    for (int i = 0; i < 16; i += 4) {
        float4 v = *(const float4*)(src + i);
        T[c0 + i][r]     = f2b(v.x);
        T[c0 + i + 1][r] = f2b(v.y);
        T[c0 + i + 2][r] = f2b(v.z);
        T[c0 + i + 3][r] = f2b(v.w);
    }
    __syncthreads();
    int rr = threadIdx.x >> 2, cc = (threadIdx.x & 3) * 16;
    size_t dstBase = (mode == 0) ? ((size_t)(h * 64 + rr) * 1024 + e0)
                                 : ((size_t)(n0 + rr) * 1024 + e0);
    uint4* dst = (uint4*)(out + dstBase + cc);
    const u16* srow = &T[rr][cc];
    dst[0] = *(const uint4*)(srow);
    dst[1] = *(const uint4*)(srow + 8);
}

// ---- fused QKV projection GEMM: 128x128 tiles, counted-vmcnt dbuf ----
__global__ __launch_bounds__(256, 2) void gemm_qkv(const u16* __restrict__ XdecB,
                                                   const u16* __restrict__ XencB,
                                                   const u16* __restrict__ WqT,
                                                   const u16* __restrict__ WkT,
                                                   const u16* __restrict__ WvT,
                                                   const float* __restrict__ bq,
                                                   const float* __restrict__ bk,
                                                   const float* __restrict__ bv,
                                                   u16* __restrict__ Qbuf,
                                                   u16* __restrict__ Kbuf,
                                                   u16* __restrict__ Vtb) {
    __shared__ __align__(16) u16 SH[17408];
    int bid0 = blockIdx.x;
    int bid  = (bid0 & 7) * 96 + (bid0 >> 3);

    const u16 *Ap, *Btp; const float* bias; u16* outp;
    int m0, n0, mode; float scale;
    if (bid < 256) {
        Ap = XdecB; Btp = WqT; bias = bq; outp = Qbuf; mode = 1; scale = QSCL;
        m0 = (bid >> 3) * 128; n0 = (bid & 7) * 128;
    } else {
        int kv = bid - 256; m0 = (kv >> 4) * 128; int nt = kv & 15; Ap = XencB; scale = 1.0f;
        if (nt < 8) { Btp = WkT; bias = bk; outp = Kbuf; mode = 1; n0 = nt * 128; }
        else        { Btp = WvT; bias = bv; outp = Vtb; mode = 2; n0 = (nt - 8) * 128; }
    }

    const int t = threadIdx.x, lane = t & 63, w = t >> 6;
    const int wr = (w >> 1) * 64, wc = (w & 1) * 64;
    const int fr = lane & 15, k0 = (lane >> 4) * 8, rr = (lane >> 4) * 4;

    const u16* srcA[2]; const u16* srcB[2]; int dstL[2];
    #pragma unroll
    for (int c = 0; c < 2; ++c) {
        int lin = c * 4096 + t * 16;
        int lo  = swz_off(lin);
        srcA[c] = Ap  + (size_t)(m0 + (lo >> 6)) * 1024 + ((lo & 63) >> 1);
        srcB[c] = Btp + (size_t)(n0 + (lo >> 6)) * 1024 + ((lo & 63) >> 1);
        dstL[c] = lin;
    }
    int aoff[4], boff[4];
    #pragma unroll
    for (int m = 0; m < 4; ++m) aoff[m] = swz_off((wr + m * 16 + fr) * 64 + k0 * 2);
    #pragma unroll
    for (int n = 0; n < 4; ++n) boff[n] = swz_off((wc + n * 16 + fr) * 64 + k0 * 2);

    f32x4 acc[4][4] = {};

    #define ASB(b) ((char*)SH + (b) * 8192)
    #define BSB(b) ((char*)SH + 16384 + (b) * 8192)
    #define QSTAGE(buf, ko) do {                               \
        _Pragma("unroll") for (int c = 0; c < 2; ++c) {        \
            GLDS16(srcA[c] + (ko), ASB(buf) + dstL[c]);        \
            GLDS16(srcB[c] + (ko), BSB(buf) + dstL[c]);        \
        }                                                      \
    } while (0)

    QSTAGE(0, 0);
    for (int kt = 0; kt < 32; ++kt) {
        int cur = kt & 1;
        if (kt) SBAR();                      // prev reads of cur^1 done -> safe overwrite
        if (kt + 1 < 32) { QSTAGE(cur ^ 1, (kt + 1) * 32); VMCNT(4); }
        else             { VMCNT(0); }
        SBAR();                              // everyone's stage(kt) complete
        SCHED0();
        const char* Ab = ASB(cur);
        const char* Bb = BSB(cur);
        bf16x8 af[4], bfr[4];
        #pragma unroll
        for (int m = 0; m < 4; ++m) af[m]  = *(const bf16x8*)(Ab + aoff[m]);
        #pragma unroll
        for (int n = 0; n < 4; ++n) bfr[n] = *(const bf16x8*)(Bb + boff[n]);
        #pragma unroll
        for (int m = 0; m < 4; ++m)
            #pragma unroll
            for (int n = 0; n < 4; ++n)
                acc[m][n] = __builtin_amdgcn_mfma_f32_16x16x32_bf16(af[m], bfr[n], acc[m][n], 0, 0, 0);
    }

    if (mode == 1 || mode == 0) {
        #pragma unroll
        for (int m = 0; m < 4; ++m) {
            int row = m0 + wr + m * 16 + rr;
            #pragma unroll
            for (int n = 0; n < 4; ++n) {
                int col = n0 + wc + n * 16 + fr;
                float bv = bias[col];
                #pragma unroll
                for (int rg = 0; rg < 4; ++rg) {
                    float v = (acc[m][n][rg] + bv) * scale;
                    int rowg = row + rg;
                    int b = rowg >> 11, s = rowg & 2047;
                    int h = col >> 6, d = col & 63;
                    outp[(((size_t)b * 16 + h) * SEQ + s) * 64 + d] = f2b(v);
                }
            }
        }
    } else {
        __syncthreads();                     // loop reads done before TR overwrite
        u16* TR = SH;
        #pragma unroll
        for (int m = 0; m < 4; ++m) {
            int srow = wr + m * 16 + rr;
            #pragma unroll
            for (int n = 0; n < 4; ++n) {
                int dcol = wc + n * 16 + fr;
                float bv = bias[n0 + dcol];
                u32 lo = cvtpk(acc[m][n][0] + bv, acc[m][n][1] + bv);
                u32 hi = cvtpk(acc[m][n][2] + bv, acc[m][n][3] + bv);
                uint2 pr = {lo, hi};
                *(uint2*)(TR + dcol * 136 + srow) = pr;
            }
        }
        __syncthreads();
        int dcol = t >> 1, hf = t & 1;
        int col = n0 + dcol;
        int h = col >> 6, d = col & 63;
        int b = m0 >> 11, s0 = (m0 & 2047) + hf * 64;
        u16* dst = Vtb + (((size_t)b * 16 + h) * 64 + d) * SEQ + s0;
        const u16* srowp = TR + dcol * 136 + hf * 64;
        #pragma unroll
        for (int i = 0; i < 8; ++i)
            ((uint4*)dst)[i] = *(const uint4*)(srowp + i * 8);
    }
    #undef ASB
    #undef BSB
}

// ---- output projection GEMM: 128x64 tiles, counted-vmcnt dbuf, f32 out ----
__global__ __launch_bounds__(256, 2) void gemm_out(const u16* __restrict__ A,
                                                   const u16* __restrict__ Bt,
                                                   const float* __restrict__ bias,
                                                   float* __restrict__ out) {
    __shared__ __align__(16) u16 As[2][128 * 32];
    __shared__ __align__(16) u16 Bs[2][64 * 32];
    int bid0 = blockIdx.x;
    int bid  = (bid0 & 7) * 64 + (bid0 >> 3);
    int m0 = (bid >> 4) * 128, n0 = (bid & 15) * 64;

    const int t = threadIdx.x, lane = t & 63, w = t >> 6;
    const int wr = w * 32;
    const int fr = lane & 15, k0 = (lane >> 4) * 8, rr = (lane >> 4) * 4;

    const u16* srcA[2]; int dstA[2];
    #pragma unroll
    for (int c = 0; c < 2; ++c) {
        int lin = c * 4096 + t * 16;
        int lo  = swz_off(lin);
        srcA[c] = A + (size_t)(m0 + (lo >> 6)) * 1024 + ((lo & 63) >> 1);
        dstA[c] = lin;
    }
    int linB = t * 16, loB = swz_off(linB);
    const u16* srcBp = Bt + (size_t)(n0 + (loB >> 6)) * 1024 + ((loB & 63) >> 1);

    int aoff[2], boff[4];
    #pragma unroll
    for (int m = 0; m < 2; ++m) aoff[m] = swz_off((wr + m * 16 + fr) * 64 + k0 * 2);
    #pragma unroll
    for (int n = 0; n < 4; ++n) boff[n] = swz_off((n * 16 + fr) * 64 + k0 * 2);

    f32x4 acc[2][4] = {};

    #define OSTAGE(buf, ko) do {                                          \
        _Pragma("unroll") for (int c = 0; c < 2; ++c)                     \
            GLDS16(srcA[c] + (ko), (char*)As[buf] + dstA[c]);             \
        GLDS16(srcBp + (ko), (char*)Bs[buf] + linB);                      \
    } while (0)

    OSTAGE(0, 0);
    for (int kt = 0; kt < 32; ++kt) {
        int cur = kt & 1;
        if (kt) SBAR();
        if (kt + 1 < 32) { OSTAGE(cur ^ 1, (kt + 1) * 32); VMCNT(3); }
        else             { VMCNT(0); }
        SBAR();
        SCHED0();
        const char* Ab = (const char*)As[cur];
        const char* Bb = (const char*)Bs[cur];
        bf16x8 af[2], bfr[4];
        #pragma unroll
        for (int m = 0; m < 2; ++m) af[m]  = *(const bf16x8*)(Ab + aoff[m]);
        #pragma unroll
        for (int n = 0; n < 4; ++n) bfr[n] = *(const bf16x8*)(Bb + boff[n]);
        #pragma unroll
        for (int m = 0; m < 2; ++m)
            #pragma unroll
            for (int n = 0; n < 4; ++n)
                acc[m][n] = __builtin_amdgcn_mfma_f32_16x16x32_bf16(af[m], bfr[n], acc[m][n], 0, 0, 0);
    }
    #undef OSTAGE

    #pragma unroll
    for (int m = 0; m < 2; ++m) {
        int row = m0 + wr + m * 16 + rr;
        #pragma unroll
        for (int n = 0; n < 4; ++n) {
            int col = n0 + n * 16 + fr;
            float bv = bias[col];
            #pragma unroll
            for (int rg = 0; rg < 4; ++rg)
                out[(size_t)(row + rg) * EMB + col] = acc[m][n][rg] + bv;
        }
    }
}

// ---- attention: 64 q/wave, LDS K/V staging (counted vmcnt), in-register softmax ----
// 4 waves x 64 q = 256 q per block; 256 blocks (1/CU). K-frag/V-frag LDS reads
// amortize over two 32-q halves -> LDS volume per q halved vs 32q/wave.
__global__ __launch_bounds__(256, 1) void attn_kernel(const u16* __restrict__ Qb,
                                                      const u16* __restrict__ Kb,
                                                      const u16* __restrict__ Vt,
                                                      u16* __restrict__ Ctx) {
    __shared__ __align__(16) u16 KS[2][64 * 64];
    __shared__ __align__(16) u16 VS[2][64 * 64];
    int id0 = blockIdx.x;
    int id  = (id0 & 7) * 32 + (id0 >> 3);   // XCD swizzle: 256 = 8*32
    int qt = id & 7, bh = id >> 3;
    const int t = threadIdx.x, lane = t & 63, w = t >> 6;
    const int ql = lane & 31, hi = lane >> 5;
    const int q0 = qt * 256 + w * 64;

    const u16* Qp = Qb + (size_t)bh * SEQ * 64;
    const u16* Kp = Kb + (size_t)bh * SEQ * 64;
    const u16* Vp = Vt + (size_t)bh * 64 * SEQ;

    bf16x8 qfA[4], qfB[4];
    #pragma unroll
    for (int s = 0; s < 4; ++s) {
        qfA[s] = *(const bf16x8*)(Qp + (size_t)(q0 + ql) * 64 + s * 16 + hi * 8);
        qfB[s] = *(const bf16x8*)(Qp + (size_t)(q0 + 32 + ql) * 64 + s * 16 + hi * 8);
    }

    const u16* ksrc[2]; const u16* vsrc[2]; int linc[2];
    #pragma unroll
    for (int c = 0; c < 2; ++c) {
        int lin = c * 4096 + t * 16;
        int row = lin >> 7;
        int lo  = lin ^ ((row & 7) << 4);
        int colE = (lo & 127) >> 1;
        linc[c] = lin;
        ksrc[c] = Kp + (size_t)row * 64 + colE;
        vsrc[c] = Vp + (size_t)row * SEQ + colE;
    }

#define STAGE(buf, kb) do {                                            \
    _Pragma("unroll") for (int c = 0; c < 2; ++c)                      \
        GLDS16(ksrc[c] + (size_t)(kb) * 64, (char*)KS[buf] + linc[c]); \
    _Pragma("unroll") for (int c = 0; c < 2; ++c)                      \
        GLDS16(vsrc[c] + (kb),              (char*)VS[buf] + linc[c]); \
} while (0)

    int koff[2][4], voff[2][2][2];
    #pragma unroll
    for (int hh = 0; hh < 2; ++hh) {
        #pragma unroll
        for (int s = 0; s < 4; ++s)
            koff[hh][s] = ((hh * 32 + ql) * 128 + s * 32 + hi * 16) ^ ((ql & 7) << 4);
        #pragma unroll
        for (int n = 0; n < 2; ++n)
            #pragma unroll
            for (int s2 = 0; s2 < 2; ++s2)
                voff[hh][n][s2] = ((ql + n * 32) * 128 + hh * 64 + s2 * 32 + hi * 16) ^ ((ql & 7) << 4);
    }

    f32x16 aA0 = {}, aA1 = {}, aB0 = {}, aB1 = {};
    float lsA = 0.f, lsB = 0.f;

#define PACK8(PA, P, o) do {                                           \
    u32 a0 = cvtpk(P[(o) + 0], P[(o) + 1]);                            \
    u32 a1 = cvtpk(P[(o) + 2], P[(o) + 3]);                            \
    u32 a2 = cvtpk(P[(o) + 4], P[(o) + 5]);                            \
    u32 a3 = cvtpk(P[(o) + 6], P[(o) + 7]);                            \
    asm("v_permlane32_swap_b32 %0, %1" : "+v"(a0), "+v"(a2));          \
    asm("v_permlane32_swap_b32 %0, %1" : "+v"(a1), "+v"(a3));          \
    uint4 pkv = {a0, a1, a2, a3};                                      \
    PA = __builtin_bit_cast(bf16x8, pkv);                              \
} while (0)

#define COMPUTE(buf, hh) do {                                                    \
    bf16x8 kf0 = *(const bf16x8*)((const char*)KS[buf] + koff[hh][0]);           \
    bf16x8 kf1 = *(const bf16x8*)((const char*)KS[buf] + koff[hh][1]);           \
    bf16x8 kf2 = *(const bf16x8*)((const char*)KS[buf] + koff[hh][2]);           \
    bf16x8 kf3 = *(const bf16x8*)((const char*)KS[buf] + koff[hh][3]);           \
    f32x16 s0 = {}, s1 = {};                                                     \
    s0 = __builtin_amdgcn_mfma_f32_32x32x16_bf16(kf0, qfA[0], s0, 0, 0, 0);      \
    s1 = __builtin_amdgcn_mfma_f32_32x32x16_bf16(kf1, qfA[1], s1, 0, 0, 0);      \
    s0 = __builtin_amdgcn_mfma_f32_32x32x16_bf16(kf2, qfA[2], s0, 0, 0, 0);      \
    s1 = __builtin_amdgcn_mfma_f32_32x32x16_bf16(kf3, qfA[3], s1, 0, 0, 0);      \
    float pA[16];                                                                \
    _Pragma("unroll") for (int r = 0; r < 16; ++r) {                             \
        pA[r] = exp2g(s0[r] + s1[r]); lsA += pA[r];                              \
    }                                                                            \
    f32x16 t0 = {}, t1 = {};                                                     \
    t0 = __builtin_amdgcn_mfma_f32_32x32x16_bf16(kf0, qfB[0], t0, 0, 0, 0);      \
    t1 = __builtin_amdgcn_mfma_f32_32x32x16_bf16(kf1, qfB[1], t1, 0, 0, 0);      \
    t0 = __builtin_amdgcn_mfma_f32_32x32x16_bf16(kf2, qfB[2], t0, 0, 0, 0);      \
    t1 = __builtin_amdgcn_mfma_f32_32x32x16_bf16(kf3, qfB[3], t1, 0, 0, 0);      \
    float pB[16];                                                                \
    _Pragma("unroll") for (int r = 0; r < 16; ++r) {                             \
        pB[r] = exp2g(t0[r] + t1[r]); lsB += pB[r];                              \
    }                                                                            \
    _Pragma("unroll") for (int s2 = 0; s2 < 2; ++s2) {                           \
        bf16x8 paA, paB;                                                         \
        PACK8(paA, pA, 8 * s2);                                                  \
        PACK8(paB, pB, 8 * s2);                                                  \
        bf16x8 v0 = *(const bf16x8*)((const char*)VS[buf] + voff[hh][0][s2]);    \
        bf16x8 v1 = *(const bf16x8*)((const char*)VS[buf] + voff[hh][1][s2]);    \
        aA0 = __builtin_amdgcn_mfma_f32_32x32x16_bf16(paA, v0, aA0, 0, 0, 0);    \
        aA1 = __builtin_amdgcn_mfma_f32_32x32x16_bf16(paA, v1, aA1, 0, 0, 0);    \
        aB0 = __builtin_amdgcn_mfma_f32_32x32x16_bf16(paB, v0, aB0, 0, 0, 0);    \
        aB1 = __builtin_amdgcn_mfma_f32_32x32x16_bf16(paB, v1, aB1, 0, 0, 0);    \
    }                                                                            \
} while (0)

    STAGE(0, 0);
    for (int it = 0; it < 32; ++it) {
        int cur = it & 1;
        if (it) SBAR();                            // prev reads done -> safe overwrite
        if (it < 31) { STAGE(cur ^ 1, (it + 1) * 64); VMCNT(4); }
        else         { VMCNT(0); }
        SBAR();                                    // everyone's stage(it) landed
        SCHED0();
        COMPUTE(cur, 0);
        COMPUTE(cur, 1);
    }

    lsA += __shfl_xor(lsA, 32, 64);
    lsB += __shfl_xor(lsB, 32, 64);
    float invA = 1.0f / lsA, invB = 1.0f / lsB;
    int b = bh >> 4, h = bh & 15;
    size_t obase = (size_t)b * SEQ * EMB + h * 64 + ql;
    #pragma unroll
    for (int r = 0; r < 16; ++r) {
        int qr = (r & 3) + 8 * (r >> 2) + 4 * hi;
        float ivA = __shfl(invA, qr, 64);
        float ivB = __shfl(invB, qr, 64);
        size_t offA = obase + (size_t)(q0 + qr) * EMB;
        size_t offB = obase + (size_t)(q0 + 32 + qr) * EMB;
        Ctx[offA]      = f2b(aA0[r] * ivA);
        Ctx[offA + 32] = f2b(aA1[r] * ivA);
        Ctx[offB]      = f2b(aB0[r] * ivB);
        Ctx[offB + 32] = f2b(aB1[r] * ivB);
    }
}

extern "C" void kernel_launch(void* const* d_in, const int* in_sizes, int n_in,
                              void* d_out, int out_size, void* d_ws, size_t ws_size,
                              hipStream_t stream) {
    const float* Xdec = (const float*)d_in[0];
    const float* Xenc = (const float*)d_in[1];
    const float* wq = (const float*)d_in[2];
    const float* bq = (const float*)d_in[3];
    const float* wk = (const float*)d_in[4];
    const float* bk = (const float*)d_in[5];
    const float* wv = (const float*)d_in[6];
    const float* bv = (const float*)d_in[7];
    const float* wo = (const float*)d_in[8];
    const float* bo = (const float*)d_in[9];

    char* ws = (char*)d_ws;
    const size_t MB = 1024ull * 1024ull;
    u16* XdecB = (u16*)(ws + 0 * MB);
    u16* XencB = (u16*)(ws + 8 * MB);
    u16* WqT   = (u16*)(ws + 16 * MB);
    u16* WkT   = (u16*)(ws + 18 * MB);
    u16* WvT   = (u16*)(ws + 20 * MB);
    u16* WoT   = (u16*)(ws + 22 * MB);
    u16* Qbuf  = (u16*)(ws + 24 * MB);
    u16* Kbuf  = (u16*)(ws + 32 * MB);
    u16* Vtb   = (u16*)(ws + 40 * MB);
    u16* CtxB  = (u16*)(ws + 48 * MB);

    convx2_kernel<<<8192, 256, 0, stream>>>(Xdec, Xenc, XdecB, XencB);
    convw4_kernel<<<1024, 256, 0, stream>>>(wq, wk, wv, wo, WqT, WkT, WvT, WoT);

    gemm_qkv<<<768, 256, 0, stream>>>(XdecB, XencB, WqT, WkT, WvT, bq, bk, bv,
                                      Qbuf, Kbuf, Vtb);

    attn_kernel<<<256, 256, 0, stream>>>(Qbuf, Kbuf, Vtb, CtxB);

    gemm_out<<<512, 256, 0, stream>>>(CtxB, WoT, bo, (float*)d_out);
}